// Round 5
// baseline (65.471 us; speedup 1.0000x reference)
//
#include <hip/hip_runtime.h>

constexpr int DSZ = 192, HSZ = 192, WSZ = 192, BSZ = 2;
constexpr int WQ = WSZ / 4;                  // 48 float4 per row
constexpr int HP = HSZ / 2;                  // 96 row-pairs per plane
constexpr int TPB = 192;                     // 3 waves: 9 blocks/CU = 27 waves, no overhang
constexpr int ITERS = 4;
constexpr int NPAIR = BSZ * DSZ * HP * WQ;   // 1,769,472 pair-tasks
constexpr int NBLOCKS = NPAIR / (TPB * ITERS);  // 2304, %8==0
constexpr int HW = HSZ * WSZ;
constexpr float SMOOTH = 1e-5f;

__device__ __forceinline__ float4 ld4(const float* __restrict__ p) {
    return *reinterpret_cast<const float4*>(p);
}

// 4-wide boundary magnitude: center row c, rows above/below hm/hn,
// planes d0/d1, scalar w-edges wl/wr
__device__ __forceinline__ void mag4(float4 c, float4 hm, float4 hn,
                                     float4 d0, float4 d1, float wl, float wr,
                                     float o[4]) {
    float gx0 = d1.x - d0.x, gx1 = d1.y - d0.y, gx2 = d1.z - d0.z, gx3 = d1.w - d0.w;
    float gy0 = hn.x - hm.x, gy1 = hn.y - hm.y, gy2 = hn.z - hm.z, gy3 = hn.w - hm.w;
    float gz0 = c.y - wl,    gz1 = c.z - c.x,   gz2 = c.w - c.y,   gz3 = wr - c.z;
    o[0] = sqrtf(fmaf(gx0, gx0, fmaf(gy0, gy0, fmaf(gz0, gz0, SMOOTH))));
    o[1] = sqrtf(fmaf(gx1, gx1, fmaf(gy1, gy1, fmaf(gz1, gz1, SMOOTH))));
    o[2] = sqrtf(fmaf(gx2, gx2, fmaf(gy2, gy2, fmaf(gz2, gz2, SMOOTH))));
    o[3] = sqrtf(fmaf(gx3, gx3, fmaf(gy3, gy3, fmaf(gz3, gz3, SMOOTH))));
}

// load the 8-voxel pair-task stencil for one array and produce two mag4s
__device__ __forceinline__ void pair_mags(const float* __restrict__ X,
                                          int d, int hp, int wq,
                                          float m0[4], float m1[4]) {
    const float4 z = make_float4(0.f, 0.f, 0.f, 0.f);
    float4 rm = (hp > 0)       ? ld4(X - WSZ)       : z;
    float4 r0 = ld4(X);
    float4 r1 = ld4(X + WSZ);
    float4 r2 = (hp < HP - 1)  ? ld4(X + 2 * WSZ)   : z;
    float4 d0a = (d > 0)       ? ld4(X - HW)        : z;
    float4 d0b = (d > 0)       ? ld4(X - HW + WSZ)  : z;
    float4 d1a = (d < DSZ - 1) ? ld4(X + HW)        : z;
    float4 d1b = (d < DSZ - 1) ? ld4(X + HW + WSZ)  : z;
    float wl0 = (wq > 0)      ? X[-1]        : 0.f;
    float wr0 = (wq < WQ - 1) ? X[4]         : 0.f;
    float wl1 = (wq > 0)      ? X[WSZ - 1]   : 0.f;
    float wr1 = (wq < WQ - 1) ? X[WSZ + 4]   : 0.f;
    mag4(r0, rm, r1, d0a, d1a, wl0, wr0, m0);   // row h
    mag4(r1, r0, r2, d0b, d1b, wl1, wr1, m1);   // row h+1
}

__global__ __launch_bounds__(TPB)
void bl_main(const float* __restrict__ pred,
             const float* __restrict__ target,
             double* __restrict__ acc) {
    // XCD-chunked swizzle: each XCD gets a contiguous slab of blocks
    const int swz = (blockIdx.x & 7) * (NBLOCKS / 8) + (blockIdx.x >> 3);
    const int pid_base = swz * (TPB * ITERS) + threadIdx.x;

    float s_pt = 0.f, s_p = 0.f, s_t = 0.f;

    #pragma unroll 1
    for (int i = 0; i < ITERS; ++i) {
        const int pid = pid_base + i * TPB;
        const int wq  = pid % WQ;
        const int rp  = pid / WQ;
        const int hp  = rp % HP;
        const int bd  = rp / HP;
        const int d   = bd % DSZ;
        const size_t off = (size_t)bd * HW + (size_t)(2 * hp) * WSZ + wq * 4;

        float pb0[4], pb1[4], tb0[4], tb1[4];
        pair_mags(pred + off,   d, hp, wq, pb0, pb1);
        pair_mags(target + off, d, hp, wq, tb0, tb1);

        #pragma unroll
        for (int j = 0; j < 4; ++j) {
            s_pt = fmaf(pb0[j], tb0[j], s_pt);
            s_pt = fmaf(pb1[j], tb1[j], s_pt);
            s_p += pb0[j] + pb1[j];
            s_t += tb0[j] + tb1[j];
        }
    }

    // 64-lane wave reduction
    #pragma unroll
    for (int off = 32; off; off >>= 1) {
        s_pt += __shfl_down(s_pt, off);
        s_p  += __shfl_down(s_p,  off);
        s_t  += __shfl_down(s_t,  off);
    }

    __shared__ float red[3][4];   // 3 waves x {pt,p,t}
    const int lane = threadIdx.x & 63;
    const int wid  = threadIdx.x >> 6;
    if (lane == 0) {
        red[wid][0] = s_pt;
        red[wid][1] = s_p;
        red[wid][2] = s_t;
    }
    __syncthreads();
    if (threadIdx.x == 0) {
        double a_pt = 0.0, a_p = 0.0, a_t = 0.0;
        #pragma unroll
        for (int k = 0; k < 3; ++k) {
            a_pt += (double)red[k][0];
            a_p  += (double)red[k][1];
            a_t  += (double)red[k][2];
        }
        atomicAdd(&acc[0],  a_pt);
        atomicAdd(&acc[8],  a_p);
        atomicAdd(&acc[16], a_t);
    }
}

__global__ void bl_final(const double* __restrict__ acc, float* __restrict__ out) {
    const double I = acc[0];
    const double Pm = acc[8];
    const double Tm = acc[16];
    const double dice = (2.0 * I + 1e-5) / (Pm + Tm + 1e-5);
    out[0] = (float)(1.0 - dice);
}

extern "C" void kernel_launch(void* const* d_in, const int* in_sizes, int n_in,
                              void* d_out, int out_size, void* d_ws, size_t ws_size,
                              hipStream_t stream) {
    const float* pred   = (const float*)d_in[0];
    const float* target = (const float*)d_in[1];
    double* acc = (double*)d_ws;

    hipMemsetAsync(d_ws, 0, 17 * sizeof(double), stream);
    bl_main<<<NBLOCKS, TPB, 0, stream>>>(pred, target, acc);
    bl_final<<<1, 1, 0, stream>>>(acc, (float*)d_out);
}

// Round 7
// 59.330 us; speedup vs baseline: 1.1035x; 1.1035x over previous
//
#include <hip/hip_runtime.h>

constexpr int DSZ = 192, HSZ = 192, WSZ = 192, BSZ = 2;
constexpr int WQ = WSZ / 4;                  // 48 float4 per row
constexpr int HP = HSZ / 2;                  // 96 row-pairs per plane
constexpr int TPB = 256;                     // R3 config (measured best)
constexpr int ITERS = 3;
constexpr int NPAIR = BSZ * DSZ * HP * WQ;   // 1,769,472 pair-tasks
constexpr int NBLOCKS = NPAIR / (TPB * ITERS);  // 2304, %8==0
constexpr int HW = HSZ * WSZ;
constexpr float SMOOTH = 1e-5f;

__device__ __forceinline__ float4 ld4(const float* __restrict__ p) {
    return *reinterpret_cast<const float4*>(p);
}

__device__ __forceinline__ float fsqrt(float x) {
    return __builtin_amdgcn_sqrtf(x);   // raw v_sqrt_f32
}

// 4-wide boundary magnitude: center row c, rows above/below hm/hn,
// planes d0/d1, scalar w-edges wl/wr
__device__ __forceinline__ void mag4(float4 c, float4 hm, float4 hn,
                                     float4 d0, float4 d1, float wl, float wr,
                                     float o[4]) {
    float gx0 = d1.x - d0.x, gx1 = d1.y - d0.y, gx2 = d1.z - d0.z, gx3 = d1.w - d0.w;
    float gy0 = hn.x - hm.x, gy1 = hn.y - hm.y, gy2 = hn.z - hm.z, gy3 = hn.w - hm.w;
    float gz0 = c.y - wl,    gz1 = c.z - c.x,   gz2 = c.w - c.y,   gz3 = wr - c.z;
    o[0] = fsqrt(fmaf(gx0, gx0, fmaf(gy0, gy0, fmaf(gz0, gz0, SMOOTH))));
    o[1] = fsqrt(fmaf(gx1, gx1, fmaf(gy1, gy1, fmaf(gz1, gz1, SMOOTH))));
    o[2] = fsqrt(fmaf(gx2, gx2, fmaf(gy2, gy2, fmaf(gz2, gz2, SMOOTH))));
    o[3] = fsqrt(fmaf(gx3, gx3, fmaf(gy3, gy3, fmaf(gz3, gz3, SMOOTH))));
}

// w-edges via cross-lane shuffle: lane l-1 owns X[-1] (its .w), lane l+1 owns X[4] (its .x)
__device__ __forceinline__ void edges(float4 r, int wq, float& wl, float& wr) {
    float up = __shfl_up(r.w, 1);
    float dn = __shfl_down(r.x, 1);
    wl = (wq > 0)      ? up : 0.f;
    wr = (wq < WQ - 1) ? dn : 0.f;
}

// load the 8-voxel pair-task stencil for one array and produce two mag4s
__device__ __forceinline__ void pair_mags(const float* __restrict__ X,
                                          int d, int hp, int wq,
                                          float m0[4], float m1[4]) {
    const float4 z = make_float4(0.f, 0.f, 0.f, 0.f);
    float4 rm = (hp > 0)       ? ld4(X - WSZ)       : z;
    float4 r0 = ld4(X);
    float4 r1 = ld4(X + WSZ);
    float4 r2 = (hp < HP - 1)  ? ld4(X + 2 * WSZ)   : z;
    float4 d0a = (d > 0)       ? ld4(X - HW)        : z;
    float4 d0b = (d > 0)       ? ld4(X - HW + WSZ)  : z;
    float4 d1a = (d < DSZ - 1) ? ld4(X + HW)        : z;
    float4 d1b = (d < DSZ - 1) ? ld4(X + HW + WSZ)  : z;
    float wl0, wr0, wl1, wr1;
    edges(r0, wq, wl0, wr0);
    edges(r1, wq, wl1, wr1);
    mag4(r0, rm, r1, d0a, d1a, wl0, wr0, m0);   // row h
    mag4(r1, r0, r2, d0b, d1b, wl1, wr1, m1);   // row h+1
}

__global__ __launch_bounds__(TPB)
void bl_main(const float* __restrict__ pred,
             const float* __restrict__ target,
             double* __restrict__ acc) {
    // XCD-chunked swizzle: each XCD gets a contiguous slab of blocks
    const int swz = (blockIdx.x & 7) * (NBLOCKS / 8) + (blockIdx.x >> 3);
    const int pid_base = swz * (TPB * ITERS) + threadIdx.x;

    float s_pt = 0.f, s_p = 0.f, s_t = 0.f;

    #pragma unroll 1
    for (int i = 0; i < ITERS; ++i) {
        const int pid = pid_base + i * TPB;
        const int wq  = pid % WQ;
        const int rp  = pid / WQ;
        const int hp  = rp % HP;
        const int bd  = rp / HP;
        const int d   = bd % DSZ;
        const size_t off = (size_t)bd * HW + (size_t)(2 * hp) * WSZ + wq * 4;

        float pb0[4], pb1[4], tb0[4], tb1[4];
        pair_mags(pred + off,   d, hp, wq, pb0, pb1);
        pair_mags(target + off, d, hp, wq, tb0, tb1);

        #pragma unroll
        for (int j = 0; j < 4; ++j) {
            s_pt = fmaf(pb0[j], tb0[j], s_pt);
            s_pt = fmaf(pb1[j], tb1[j], s_pt);
            s_p += pb0[j] + pb1[j];
            s_t += tb0[j] + tb1[j];
        }
    }

    // 64-lane wave reduction
    #pragma unroll
    for (int off = 32; off; off >>= 1) {
        s_pt += __shfl_down(s_pt, off);
        s_p  += __shfl_down(s_p,  off);
        s_t  += __shfl_down(s_t,  off);
    }

    __shared__ float red[4][4];   // 4 waves x {pt,p,t}
    const int lane = threadIdx.x & 63;
    const int wid  = threadIdx.x >> 6;
    if (lane == 0) {
        red[wid][0] = s_pt;
        red[wid][1] = s_p;
        red[wid][2] = s_t;
    }
    __syncthreads();
    if (threadIdx.x == 0) {
        double a_pt = 0.0, a_p = 0.0, a_t = 0.0;
        #pragma unroll
        for (int k = 0; k < 4; ++k) {
            a_pt += (double)red[k][0];
            a_p  += (double)red[k][1];
            a_t  += (double)red[k][2];
        }
        atomicAdd(&acc[0],  a_pt);
        atomicAdd(&acc[8],  a_p);
        atomicAdd(&acc[16], a_t);
    }
}

__global__ void bl_final(const double* __restrict__ acc, float* __restrict__ out) {
    const double I = acc[0];
    const double Pm = acc[8];
    const double Tm = acc[16];
    const double dice = (2.0 * I + 1e-5) / (Pm + Tm + 1e-5);
    out[0] = (float)(1.0 - dice);
}

extern "C" void kernel_launch(void* const* d_in, const int* in_sizes, int n_in,
                              void* d_out, int out_size, void* d_ws, size_t ws_size,
                              hipStream_t stream) {
    const float* pred   = (const float*)d_in[0];
    const float* target = (const float*)d_in[1];
    double* acc = (double*)d_ws;

    (void)hipMemsetAsync(d_ws, 0, 17 * sizeof(double), stream);
    bl_main<<<NBLOCKS, TPB, 0, stream>>>(pred, target, acc);
    bl_final<<<1, 1, 0, stream>>>(acc, (float*)d_out);
}

// Round 8
// 57.901 us; speedup vs baseline: 1.1307x; 1.0247x over previous
//
#include <hip/hip_runtime.h>

constexpr int DSZ = 192, HSZ = 192, WSZ = 192, BSZ = 2;
constexpr int WQ = WSZ / 4;                  // 48 float4 per row
constexpr int HP = HSZ / 2;                  // 96 row-pairs per plane
constexpr int DT = 3;                        // planes marched per thread-chunk
constexpr int CHUNKS = DSZ / DT;             // 64 d-chunks
constexpr int TPB = 256;
constexpr int NCOL = BSZ * HP * WQ;          // 9216 (b,hp,wq) columns
constexpr int NBLOCKS = NCOL * CHUNKS / TPB; // 2304, %8==0
constexpr int HW = HSZ * WSZ;
constexpr float SMOOTH = 1e-5f;

__device__ __forceinline__ float4 ld4(const float* __restrict__ p) {
    return *reinterpret_cast<const float4*>(p);
}

__device__ __forceinline__ float fsqrt(float x) {
    return __builtin_amdgcn_sqrtf(x);   // raw v_sqrt_f32
}

// 4-wide boundary magnitude
__device__ __forceinline__ void mag4(float4 c, float4 hm, float4 hn,
                                     float4 d0, float4 d1, float wl, float wr,
                                     float o[4]) {
    float gx0 = d1.x - d0.x, gx1 = d1.y - d0.y, gx2 = d1.z - d0.z, gx3 = d1.w - d0.w;
    float gy0 = hn.x - hm.x, gy1 = hn.y - hm.y, gy2 = hn.z - hm.z, gy3 = hn.w - hm.w;
    float gz0 = c.y - wl,    gz1 = c.z - c.x,   gz2 = c.w - c.y,   gz3 = wr - c.z;
    o[0] = fsqrt(fmaf(gx0, gx0, fmaf(gy0, gy0, fmaf(gz0, gz0, SMOOTH))));
    o[1] = fsqrt(fmaf(gx1, gx1, fmaf(gy1, gy1, fmaf(gz1, gz1, SMOOTH))));
    o[2] = fsqrt(fmaf(gx2, gx2, fmaf(gy2, gy2, fmaf(gz2, gz2, SMOOTH))));
    o[3] = fsqrt(fmaf(gx3, gx3, fmaf(gy3, gy3, fmaf(gz3, gz3, SMOOTH))));
}

// w-edges via cross-lane shuffle: lane l-1 owns X[-1] (its .w), lane l+1 owns X[4] (its .x)
__device__ __forceinline__ void edges(float4 r, int wq, float& wl, float& wr) {
    float up = __shfl_up(r.w, 1);
    float dn = __shfl_down(r.x, 1);
    wl = (wq > 0)      ? up : 0.f;
    wr = (wq < WQ - 1) ? dn : 0.f;
}

__global__ __launch_bounds__(TPB)
void bl_main(const float* __restrict__ pred,
             const float* __restrict__ target,
             double* __restrict__ acc) {
    // XCD-chunked swizzle: each XCD gets a contiguous slab of blocks
    const int swz = (blockIdx.x & 7) * (NBLOCKS / 8) + (blockIdx.x >> 3);
    const int pid = swz * TPB + threadIdx.x;

    const int wq = pid % WQ;
    int t        = pid / WQ;
    const int hp = t % HP;
    t            = t / HP;
    const int dc = t % CHUNKS;
    const int b  = t / CHUNKS;
    const int d0 = dc * DT;

    const float4 z = make_float4(0.f, 0.f, 0.f, 0.f);
    const float* __restrict__ P = pred   + (size_t)b * DSZ * HW + (size_t)(2 * hp) * WSZ + wq * 4;
    const float* __restrict__ T = target + (size_t)b * DSZ * HW + (size_t)(2 * hp) * WSZ + wq * 4;

    // rolling 2-plane window: rows h (r0) and h+1 (r1) at planes d-1 (m), d (c)
    float4 p0m, p0c, p1m, p1c, t0m, t0c, t1m, t1c;
    {
        const size_t dOff = (size_t)d0 * HW;
        p0c = ld4(P + dOff);
        p1c = ld4(P + WSZ + dOff);
        t0c = ld4(T + dOff);
        t1c = ld4(T + WSZ + dOff);
        if (d0 > 0) {
            const size_t dmOff = dOff - HW;
            p0m = ld4(P + dmOff);
            p1m = ld4(P + WSZ + dmOff);
            t0m = ld4(T + dmOff);
            t1m = ld4(T + WSZ + dmOff);
        } else {
            p0m = z; p1m = z; t0m = z; t1m = z;
        }
    }

    float s_pt = 0.f, s_p = 0.f, s_t = 0.f;

    #pragma unroll
    for (int s = 0; s < DT; ++s) {
        const int d = d0 + s;
        const size_t dOff  = (size_t)d * HW;
        const size_t dpOff = dOff + HW;

        // this step's loads (8 per array-pair step, all independent)
        float4 p0p = (d < DSZ - 1)  ? ld4(P + dpOff)        : z;
        float4 p1p = (d < DSZ - 1)  ? ld4(P + WSZ + dpOff)  : z;
        float4 t0p = (d < DSZ - 1)  ? ld4(T + dpOff)        : z;
        float4 t1p = (d < DSZ - 1)  ? ld4(T + WSZ + dpOff)  : z;
        float4 phm = (hp > 0)       ? ld4(P - WSZ + dOff)   : z;
        float4 thm = (hp > 0)       ? ld4(T - WSZ + dOff)   : z;
        float4 phn = (hp < HP - 1)  ? ld4(P + 2 * WSZ + dOff) : z;
        float4 thn = (hp < HP - 1)  ? ld4(T + 2 * WSZ + dOff) : z;

        float wl, wr;
        float pb0[4], pb1[4], tb0[4], tb1[4];
        edges(p0c, wq, wl, wr);
        mag4(p0c, phm, p1c, p0m, p0p, wl, wr, pb0);
        edges(p1c, wq, wl, wr);
        mag4(p1c, p0c, phn, p1m, p1p, wl, wr, pb1);
        edges(t0c, wq, wl, wr);
        mag4(t0c, thm, t1c, t0m, t0p, wl, wr, tb0);
        edges(t1c, wq, wl, wr);
        mag4(t1c, t0c, thn, t1m, t1p, wl, wr, tb1);

        #pragma unroll
        for (int j = 0; j < 4; ++j) {
            s_pt = fmaf(pb0[j], tb0[j], s_pt);
            s_pt = fmaf(pb1[j], tb1[j], s_pt);
            s_p += pb0[j] + pb1[j];
            s_t += tb0[j] + tb1[j];
        }

        // slide window
        p0m = p0c; p0c = p0p;
        p1m = p1c; p1c = p1p;
        t0m = t0c; t0c = t0p;
        t1m = t1c; t1c = t1p;
    }

    // 64-lane wave reduction
    #pragma unroll
    for (int off = 32; off; off >>= 1) {
        s_pt += __shfl_down(s_pt, off);
        s_p  += __shfl_down(s_p,  off);
        s_t  += __shfl_down(s_t,  off);
    }

    __shared__ float red[4][4];   // 4 waves x {pt,p,t}
    const int lane = threadIdx.x & 63;
    const int wid  = threadIdx.x >> 6;
    if (lane == 0) {
        red[wid][0] = s_pt;
        red[wid][1] = s_p;
        red[wid][2] = s_t;
    }
    __syncthreads();
    if (threadIdx.x == 0) {
        double a_pt = 0.0, a_p = 0.0, a_t = 0.0;
        #pragma unroll
        for (int k = 0; k < 4; ++k) {
            a_pt += (double)red[k][0];
            a_p  += (double)red[k][1];
            a_t  += (double)red[k][2];
        }
        atomicAdd(&acc[0],  a_pt);
        atomicAdd(&acc[8],  a_p);
        atomicAdd(&acc[16], a_t);
    }
}

__global__ void bl_final(const double* __restrict__ acc, float* __restrict__ out) {
    const double I = acc[0];
    const double Pm = acc[8];
    const double Tm = acc[16];
    const double dice = (2.0 * I + 1e-5) / (Pm + Tm + 1e-5);
    out[0] = (float)(1.0 - dice);
}

extern "C" void kernel_launch(void* const* d_in, const int* in_sizes, int n_in,
                              void* d_out, int out_size, void* d_ws, size_t ws_size,
                              hipStream_t stream) {
    const float* pred   = (const float*)d_in[0];
    const float* target = (const float*)d_in[1];
    double* acc = (double*)d_ws;

    (void)hipMemsetAsync(d_ws, 0, 17 * sizeof(double), stream);
    bl_main<<<NBLOCKS, TPB, 0, stream>>>(pred, target, acc);
    bl_final<<<1, 1, 0, stream>>>(acc, (float*)d_out);
}